// Round 1
// baseline (247.928 us; speedup 1.0000x reference)
//
#include <hip/hip_runtime.h>
#include <hip/hip_bf16.h>
#include <math.h>

// WeightsOnlyAttention: qk proj (bf16 MFMA) -> causal softmax over k ->
// LayerNorm across S=16 heads -> out (4,16,1024,1024) fp32.
// B=4 P=1024 E=768 S=16 H=64.

typedef __bf16 bf16_t;
typedef __bf16 bf16x4_t __attribute__((ext_vector_type(4)));
typedef __bf16 bf16x8_t __attribute__((ext_vector_type(8)));
typedef float  f32x4_t  __attribute__((ext_vector_type(4)));

#define DEV __device__ __forceinline__
static constexpr float kLog2e = 1.4426950408889634f;

DEV void gload_lds16(const bf16_t* g, bf16_t* l) {
  __builtin_amdgcn_global_load_lds(
      (const __attribute__((address_space(1))) void*)g,
      (__attribute__((address_space(3))) void*)l, 16, 0, 0);
}

// ---------------- x (f32) -> xb (bf16), 4096x768 ----------------
__global__ __launch_bounds__(256) void k_cvt_x(const float* __restrict__ x,
                                               bf16_t* __restrict__ xb) {
  size_t i = ((size_t)blockIdx.x * 256 + threadIdx.x) * 8;
  f32x4_t a = *(const f32x4_t*)(x + i);
  f32x4_t b = *(const f32x4_t*)(x + i + 4);
  bf16x8_t o = {(bf16_t)a[0], (bf16_t)a[1], (bf16_t)a[2], (bf16_t)a[3],
                (bf16_t)b[0], (bf16_t)b[1], (bf16_t)b[2], (bf16_t)b[3]};
  *(bf16x8_t*)(xb + i) = o;
}

// ------------- W [768][2048] f32 -> Wt [2048][768] bf16 -------------
__global__ __launch_bounds__(256) void k_tr_w(const float* __restrict__ W,
                                              bf16_t* __restrict__ Wt) {
  __shared__ float t[32][33];
  int n0 = blockIdx.x * 32, e0 = blockIdx.y * 32;
  int tx = threadIdx.x & 31, ty = threadIdx.x >> 5;  // 32x8
#pragma unroll
  for (int i = 0; i < 4; i++)
    t[ty + 8 * i][tx] = W[(size_t)(e0 + ty + 8 * i) * 2048 + n0 + tx];
  __syncthreads();
#pragma unroll
  for (int i = 0; i < 4; i++)
    Wt[(size_t)(n0 + ty + 8 * i) * 768 + e0 + tx] = (bf16_t)t[tx][ty + 8 * i];
}

// ---------------- projection GEMM: C = xb * Wt^T + bias ----------------
// M=4096 (b,p), N=2048 (qk,s,h), K=768. 128x128 tile, BK=32, 4 waves.
// Epilogue: q = (C+b)*0.125 -> q_ws[b][s][p][h] bf16 ; k -> k_ws.
__global__ __launch_bounds__(256) void k_proj(const bf16_t* __restrict__ xb,
                                              const bf16_t* __restrict__ Wt,
                                              const float* __restrict__ bias,
                                              bf16_t* __restrict__ q_ws,
                                              bf16_t* __restrict__ k_ws) {
  __shared__ bf16_t As[128 * 32];
  __shared__ bf16_t Bs[128 * 32];
  const int tid = threadIdx.x;
  const int lane = tid & 63;
  const int w = tid >> 6;
  const int m0 = blockIdx.y * 128;
  const int n0 = blockIdx.x * 128;
  const int mw = (w >> 1) * 64, nw = (w & 1) * 64;

  f32x4_t zz = {0.f, 0.f, 0.f, 0.f};
  f32x4_t acc[4][4];
#pragma unroll
  for (int mt = 0; mt < 4; mt++)
#pragma unroll
    for (int nt = 0; nt < 4; nt++) acc[mt][nt] = zz;

  for (int k0 = 0; k0 < 768; k0 += 32) {
    __syncthreads();
#pragma unroll
    for (int i = 0; i < 2; i++) {
      int cbase = w * 128 + i * 64;     // 16B-chunk base for this wave-instr
      int c = cbase + lane;             // chunk: row = c>>2, 8-elem quarter = c&3
      int r = c >> 2, q8 = c & 3;
      gload_lds16(xb + (size_t)(m0 + r) * 768 + k0 + q8 * 8, As + cbase * 8);
      gload_lds16(Wt + (size_t)(n0 + r) * 768 + k0 + q8 * 8, Bs + cbase * 8);
    }
    __syncthreads();
    bf16x8_t a[4], b[4];
#pragma unroll
    for (int mt = 0; mt < 4; mt++)
      a[mt] = *(const bf16x8_t*)(As + (mw + mt * 16 + (lane & 15)) * 32 + (lane >> 4) * 8);
#pragma unroll
    for (int nt = 0; nt < 4; nt++)
      b[nt] = *(const bf16x8_t*)(Bs + (nw + nt * 16 + (lane & 15)) * 32 + (lane >> 4) * 8);
#pragma unroll
    for (int mt = 0; mt < 4; mt++)
#pragma unroll
      for (int nt = 0; nt < 4; nt++)
        acc[mt][nt] = __builtin_amdgcn_mfma_f32_16x16x32_bf16(a[mt], b[nt], acc[mt][nt], 0, 0, 0);
  }

#pragma unroll
  for (int mt = 0; mt < 4; mt++) {
    int row0 = mw + mt * 16 + (lane >> 4) * 4;
#pragma unroll
    for (int nt = 0; nt < 4; nt++) {
      int col = nw + nt * 16 + (lane & 15);
      int n = n0 + col;
      int s = (n >> 6) & 15, h = n & 63, qk = n >> 10;
      float bv = bias[n];
#pragma unroll
      for (int j = 0; j < 4; j++) {
        int m = m0 + row0 + j;
        int bi = m >> 10, p = m & 1023;
        float v = acc[mt][nt][j] + bv;
        size_t off = ((size_t)(bi * 16 + s) * 1024 + p) * 64 + h;
        if (qk == 0) q_ws[off] = (bf16_t)(v * 0.125f);
        else         k_ws[off] = (bf16_t)v;
      }
    }
  }
}

// ---------------- rl[b][s][p] = 1 / sum_{k<=p} exp(score) ----------------
// grid (16 pblocks, 64 bs), 4 waves x 16 rows. Scores via 16x16x32 MFMA.
__global__ __launch_bounds__(256) void k_sumexp(const bf16_t* __restrict__ q_ws,
                                                const bf16_t* __restrict__ k_ws,
                                                float* __restrict__ rl_ws) {
  const int tid = threadIdx.x, lane = tid & 63, w = tid >> 6;
  const int bs = blockIdx.y;
  const int r0 = blockIdx.x * 64 + w * 16;
  const size_t base = (size_t)bs * 65536;  // 1024*64

  const bf16_t* qrow = q_ws + base + (size_t)(r0 + (lane & 15)) * 64 + (lane >> 4) * 8;
  bf16x8_t A0 = *(const bf16x8_t*)(qrow);
  bf16x8_t A1 = *(const bf16x8_t*)(qrow + 32);

  float sum[4] = {0.f, 0.f, 0.f, 0.f};
  const int ktmax = (r0 + 15) >> 4;
  for (int kt = 0; kt <= ktmax; kt++) {
    const bf16_t* krow = k_ws + base + (size_t)(kt * 16 + (lane & 15)) * 64 + (lane >> 4) * 8;
    bf16x8_t B0 = *(const bf16x8_t*)(krow);
    bf16x8_t B1 = *(const bf16x8_t*)(krow + 32);
    f32x4_t z = {0.f, 0.f, 0.f, 0.f};
    f32x4_t sc = __builtin_amdgcn_mfma_f32_16x16x32_bf16(A0, B0, z, 0, 0, 0);
    sc = __builtin_amdgcn_mfma_f32_16x16x32_bf16(A1, B1, sc, 0, 0, 0);
    int col = kt * 16 + (lane & 15);
#pragma unroll
    for (int j = 0; j < 4; j++) {
      int row = r0 + (lane >> 4) * 4 + j;
      float e = (col <= row) ? exp2f(sc[j] * kLog2e) : 0.f;
      sum[j] += e;
    }
  }
#pragma unroll
  for (int j = 0; j < 4; j++)
#pragma unroll
    for (int msk = 1; msk < 16; msk <<= 1) sum[j] += __shfl_xor(sum[j], msk, 64);
  if ((lane & 15) == 0) {
#pragma unroll
    for (int j = 0; j < 4; j++)
      rl_ws[(size_t)bs * 1024 + r0 + (lane >> 4) * 4 + j] = 1.0f / sum[j];
  }
}

// ------- final: recompute scores, w=exp*rl, LN over 16 heads, write -------
// grid (32 kb, 32 pb, 4 b), 4 waves = 2x2 of 16x16 (p,k) tiles.
// C-layout: each lane holds 4 cells; looping s keeps the full 16-head
// vector per cell lane-local -> mean/var with zero cross-lane traffic.
__global__ __launch_bounds__(256) void k_final(const bf16_t* __restrict__ q_ws,
                                               const bf16_t* __restrict__ k_ws,
                                               const float* __restrict__ rl_ws,
                                               const float* __restrict__ ln_scale,
                                               const float* __restrict__ ln_bias,
                                               float* __restrict__ out) {
  const int tid = threadIdx.x, lane = tid & 63, w = tid >> 6;
  const int bb = blockIdx.z, pb = blockIdx.y, kb = blockIdx.x;
  const int pbase = pb * 32, kbase = kb * 32;

  if (kbase > pbase + 31) {  // fully masked: w=0 for all heads -> out = ln_bias
    int pl = tid >> 3, kq = (tid & 7) * 4;
#pragma unroll
    for (int s = 0; s < 16; s++) {
      float bv = ln_bias[s];
      f32x4_t v = {bv, bv, bv, bv};
      *(f32x4_t*)(out + ((size_t)(bb * 16 + s) * 1024 + pbase + pl) * 1024 + kbase + kq) = v;
    }
    return;
  }

  const int p_off = pbase + (w >> 1) * 16;
  const int k_off = kbase + (w & 1) * 16;
  const int kcol = k_off + (lane & 15);
  const int rloc = (lane >> 4) * 4;

  float wreg[16][4];
  float sum[4] = {0.f, 0.f, 0.f, 0.f}, ssq[4] = {0.f, 0.f, 0.f, 0.f};
#pragma unroll
  for (int s = 0; s < 16; s++) {
    size_t base = (size_t)(bb * 16 + s) * 65536;
    const bf16_t* qrow = q_ws + base + (size_t)(p_off + (lane & 15)) * 64 + (lane >> 4) * 8;
    const bf16_t* krow = k_ws + base + (size_t)kcol * 64 + (lane >> 4) * 8;
    bf16x8_t A0 = *(const bf16x8_t*)(qrow);
    bf16x8_t A1 = *(const bf16x8_t*)(qrow + 32);
    bf16x8_t B0 = *(const bf16x8_t*)(krow);
    bf16x8_t B1 = *(const bf16x8_t*)(krow + 32);
    f32x4_t z = {0.f, 0.f, 0.f, 0.f};
    f32x4_t sc = __builtin_amdgcn_mfma_f32_16x16x32_bf16(A0, B0, z, 0, 0, 0);
    sc = __builtin_amdgcn_mfma_f32_16x16x32_bf16(A1, B1, sc, 0, 0, 0);
    const float* rlp = rl_ws + (size_t)(bb * 16 + s) * 1024 + p_off + rloc;
#pragma unroll
    for (int j = 0; j < 4; j++) {
      int prow = p_off + rloc + j;
      float wv = (kcol <= prow) ? exp2f(sc[j] * kLog2e) * rlp[j] : 0.f;
      wreg[s][j] = wv;
      sum[j] += wv;
      ssq[j] = fmaf(wv, wv, ssq[j]);
    }
  }
  float mu[4], rstd[4];
#pragma unroll
  for (int j = 0; j < 4; j++) {
    mu[j] = sum[j] * 0.0625f;
    float var = ssq[j] * 0.0625f - mu[j] * mu[j];
    rstd[j] = rsqrtf(var + 1e-5f);
  }
#pragma unroll
  for (int s = 0; s < 16; s++) {
    float scl = ln_scale[s], bi = ln_bias[s];
    size_t ob = (size_t)(bb * 16 + s) * 1024;
#pragma unroll
    for (int j = 0; j < 4; j++)
      out[(ob + p_off + rloc + j) * 1024 + kcol] = (wreg[s][j] - mu[j]) * rstd[j] * scl + bi;
  }
}

extern "C" void kernel_launch(void* const* d_in, const int* in_sizes, int n_in,
                              void* d_out, int out_size, void* d_ws, size_t ws_size,
                              hipStream_t stream) {
  (void)in_sizes; (void)n_in; (void)out_size; (void)ws_size;
  const float* x        = (const float*)d_in[0];
  // d_in[1] = mask (causal tril; structure hardcoded)
  const float* W        = (const float*)d_in[2];
  const float* bias     = (const float*)d_in[3];
  const float* ln_scale = (const float*)d_in[4];
  const float* ln_bias  = (const float*)d_in[5];
  float* out = (float*)d_out;

  char* ws = (char*)d_ws;
  bf16_t* q_ws = (bf16_t*)ws;                    //  8,388,608 B [b][s][p][h]
  bf16_t* k_ws = (bf16_t*)(ws + 8388608);        //  8,388,608 B
  float*  rl_ws = (float*)(ws + 16777216);       //    262,144 B [b][s][p]
  bf16_t* xb   = (bf16_t*)(ws + 17039360);       //  6,291,456 B [4096][768]
  bf16_t* Wt   = (bf16_t*)(ws + 23330816);       //  3,145,728 B [2048][768]

  k_cvt_x<<<dim3(1536), 256, 0, stream>>>(x, xb);
  k_tr_w <<<dim3(64, 24), 256, 0, stream>>>(W, Wt);
  k_proj <<<dim3(16, 32), 256, 0, stream>>>(xb, Wt, bias, q_ws, k_ws);
  k_sumexp<<<dim3(16, 64), 256, 0, stream>>>(q_ws, k_ws, rl_ws);
  k_final<<<dim3(32, 32, 4), 256, 0, stream>>>(q_ws, k_ws, rl_ws, ln_scale, ln_bias, out);
}

// Round 2
// 231.918 us; speedup vs baseline: 1.0690x; 1.0690x over previous
//
#include <hip/hip_runtime.h>
#include <hip/hip_bf16.h>
#include <math.h>

// WeightsOnlyAttention: qk proj (bf16 MFMA) -> causal softmax over k ->
// LayerNorm across S=16 heads -> out (4,16,1024,1024) fp32.
// B=4 P=1024 E=768 S=16 H=64.

typedef __bf16 bf16_t;
typedef __bf16 bf16x4_t __attribute__((ext_vector_type(4)));
typedef __bf16 bf16x8_t __attribute__((ext_vector_type(8)));
typedef float  f32x4_t  __attribute__((ext_vector_type(4)));

#define DEV __device__ __forceinline__
static constexpr float kLog2e = 1.4426950408889634f;

DEV void gload_lds16(const bf16_t* g, bf16_t* l) {
  __builtin_amdgcn_global_load_lds(
      (const __attribute__((address_space(1))) void*)g,
      (__attribute__((address_space(3))) void*)l, 16, 0, 0);
}

// ---------------- x (f32) -> xb (bf16), 4096x768 ----------------
__global__ __launch_bounds__(256) void k_cvt_x(const float* __restrict__ x,
                                               bf16_t* __restrict__ xb) {
  size_t i = ((size_t)blockIdx.x * 256 + threadIdx.x) * 8;
  f32x4_t a = *(const f32x4_t*)(x + i);
  f32x4_t b = *(const f32x4_t*)(x + i + 4);
  bf16x8_t o = {(bf16_t)a[0], (bf16_t)a[1], (bf16_t)a[2], (bf16_t)a[3],
                (bf16_t)b[0], (bf16_t)b[1], (bf16_t)b[2], (bf16_t)b[3]};
  *(bf16x8_t*)(xb + i) = o;
}

// ------------- W [768][2048] f32 -> Wt [2048][768] bf16 -------------
__global__ __launch_bounds__(256) void k_tr_w(const float* __restrict__ W,
                                              bf16_t* __restrict__ Wt) {
  __shared__ float t[32][33];
  int n0 = blockIdx.x * 32, e0 = blockIdx.y * 32;
  int tx = threadIdx.x & 31, ty = threadIdx.x >> 5;  // 32x8
#pragma unroll
  for (int i = 0; i < 4; i++)
    t[ty + 8 * i][tx] = W[(size_t)(e0 + ty + 8 * i) * 2048 + n0 + tx];
  __syncthreads();
#pragma unroll
  for (int i = 0; i < 4; i++)
    Wt[(size_t)(n0 + ty + 8 * i) * 768 + e0 + tx] = (bf16_t)t[tx][ty + 8 * i];
}

// ---------------- projection GEMM: C = xb * Wt^T + bias ----------------
// M=4096 (b,p), N=2048 (qk,s,h), K=768. 128x128 tile, BK=32, 4 waves.
// Epilogue: q = (C+b)*0.125 -> q_ws[b][s][p][h] bf16 ; k -> k_ws.
__global__ __launch_bounds__(256) void k_proj(const bf16_t* __restrict__ xb,
                                              const bf16_t* __restrict__ Wt,
                                              const float* __restrict__ bias,
                                              bf16_t* __restrict__ q_ws,
                                              bf16_t* __restrict__ k_ws) {
  __shared__ bf16_t As[128 * 32];
  __shared__ bf16_t Bs[128 * 32];
  const int tid = threadIdx.x;
  const int lane = tid & 63;
  const int w = tid >> 6;
  const int m0 = blockIdx.y * 128;
  const int n0 = blockIdx.x * 128;
  const int mw = (w >> 1) * 64, nw = (w & 1) * 64;

  f32x4_t zz = {0.f, 0.f, 0.f, 0.f};
  f32x4_t acc[4][4];
#pragma unroll
  for (int mt = 0; mt < 4; mt++)
#pragma unroll
    for (int nt = 0; nt < 4; nt++) acc[mt][nt] = zz;

  for (int k0 = 0; k0 < 768; k0 += 32) {
    __syncthreads();
#pragma unroll
    for (int i = 0; i < 2; i++) {
      int cbase = w * 128 + i * 64;     // 16B-chunk base for this wave-instr
      int c = cbase + lane;             // chunk: row = c>>2, 8-elem quarter = c&3
      int r = c >> 2, q8 = c & 3;
      gload_lds16(xb + (size_t)(m0 + r) * 768 + k0 + q8 * 8, As + cbase * 8);
      gload_lds16(Wt + (size_t)(n0 + r) * 768 + k0 + q8 * 8, Bs + cbase * 8);
    }
    __syncthreads();
    bf16x8_t a[4], b[4];
#pragma unroll
    for (int mt = 0; mt < 4; mt++)
      a[mt] = *(const bf16x8_t*)(As + (mw + mt * 16 + (lane & 15)) * 32 + (lane >> 4) * 8);
#pragma unroll
    for (int nt = 0; nt < 4; nt++)
      b[nt] = *(const bf16x8_t*)(Bs + (nw + nt * 16 + (lane & 15)) * 32 + (lane >> 4) * 8);
#pragma unroll
    for (int mt = 0; mt < 4; mt++)
#pragma unroll
      for (int nt = 0; nt < 4; nt++)
        acc[mt][nt] = __builtin_amdgcn_mfma_f32_16x16x32_bf16(a[mt], b[nt], acc[mt][nt], 0, 0, 0);
  }

#pragma unroll
  for (int mt = 0; mt < 4; mt++) {
    int row0 = mw + mt * 16 + (lane >> 4) * 4;
#pragma unroll
    for (int nt = 0; nt < 4; nt++) {
      int col = nw + nt * 16 + (lane & 15);
      int n = n0 + col;
      int s = (n >> 6) & 15, h = n & 63, qk = n >> 10;
      float bv = bias[n];
#pragma unroll
      for (int j = 0; j < 4; j++) {
        int m = m0 + row0 + j;
        int bi = m >> 10, p = m & 1023;
        float v = acc[mt][nt][j] + bv;
        size_t off = ((size_t)(bi * 16 + s) * 1024 + p) * 64 + h;
        if (qk == 0) q_ws[off] = (bf16_t)(v * 0.125f);
        else         k_ws[off] = (bf16_t)v;
      }
    }
  }
}

// ---------------- rl[b][s][p] = 1 / sum_{k<=p} exp(score) ----------------
// grid (16 pblocks, 64 bs), 4 waves x 16 rows. Scores via 16x16x32 MFMA.
__global__ __launch_bounds__(256) void k_sumexp(const bf16_t* __restrict__ q_ws,
                                                const bf16_t* __restrict__ k_ws,
                                                float* __restrict__ rl_ws) {
  const int tid = threadIdx.x, lane = tid & 63, w = tid >> 6;
  const int bs = blockIdx.y;
  const int r0 = blockIdx.x * 64 + w * 16;
  const size_t base = (size_t)bs * 65536;  // 1024*64

  const bf16_t* qrow = q_ws + base + (size_t)(r0 + (lane & 15)) * 64 + (lane >> 4) * 8;
  bf16x8_t A0 = *(const bf16x8_t*)(qrow);
  bf16x8_t A1 = *(const bf16x8_t*)(qrow + 32);

  float sum[4] = {0.f, 0.f, 0.f, 0.f};
  const int ktmax = (r0 + 15) >> 4;
  for (int kt = 0; kt <= ktmax; kt++) {
    const bf16_t* krow = k_ws + base + (size_t)(kt * 16 + (lane & 15)) * 64 + (lane >> 4) * 8;
    bf16x8_t B0 = *(const bf16x8_t*)(krow);
    bf16x8_t B1 = *(const bf16x8_t*)(krow + 32);
    f32x4_t z = {0.f, 0.f, 0.f, 0.f};
    f32x4_t sc = __builtin_amdgcn_mfma_f32_16x16x32_bf16(A0, B0, z, 0, 0, 0);
    sc = __builtin_amdgcn_mfma_f32_16x16x32_bf16(A1, B1, sc, 0, 0, 0);
    int col = kt * 16 + (lane & 15);
#pragma unroll
    for (int j = 0; j < 4; j++) {
      int row = r0 + (lane >> 4) * 4 + j;
      float e = (col <= row) ? exp2f(sc[j] * kLog2e) : 0.f;
      sum[j] += e;
    }
  }
#pragma unroll
  for (int j = 0; j < 4; j++)
#pragma unroll
    for (int msk = 1; msk < 16; msk <<= 1) sum[j] += __shfl_xor(sum[j], msk, 64);
  if ((lane & 15) == 0) {
#pragma unroll
    for (int j = 0; j < 4; j++)
      rl_ws[(size_t)bs * 1024 + r0 + (lane >> 4) * 4 + j] = 1.0f / sum[j];
  }
}

// ------- final: recompute scores, w=exp*rl, LN over 16 heads, write -------
// grid (32 kb, 32 pb, 4 b), 4 waves = 2x2 of 16x16 (p,k) tiles.
// SWAPPED operands: sc = mfma(K, Q) so C[r][c] = score[p=c][k=r]:
// each lane owns one p (lane&15) and 4 CONSECUTIVE k -> f32x4 stores.
// Two passes over s (sum/ssq then write) keep live state to ~8 regs:
// no wreg[16][4] spill, deep load pipelining, high occupancy.
__global__ __launch_bounds__(256) void k_final(const bf16_t* __restrict__ q_ws,
                                               const bf16_t* __restrict__ k_ws,
                                               const float* __restrict__ rl_ws,
                                               const float* __restrict__ ln_scale,
                                               const float* __restrict__ ln_bias,
                                               float* __restrict__ out) {
  const int tid = threadIdx.x, lane = tid & 63, w = tid >> 6;
  const int bb = blockIdx.z, pb = blockIdx.y, kb = blockIdx.x;
  const int pbase = pb * 32, kbase = kb * 32;

  if (kbase > pbase + 31) {  // fully masked: w=0 for all heads -> out = ln_bias
    int pl = tid >> 3, kq = (tid & 7) * 4;
#pragma unroll
    for (int s = 0; s < 16; s++) {
      float bv = ln_bias[s];
      f32x4_t v = {bv, bv, bv, bv};
      *(f32x4_t*)(out + ((size_t)(bb * 16 + s) * 1024 + pbase + pl) * 1024 + kbase + kq) = v;
    }
    return;
  }

  const int p_off = pbase + ((w >> 1) << 4);
  const int k_off = kbase + ((w & 1) << 4);
  const int p = p_off + (lane & 15);
  const int kloc = (lane >> 4) * 4;   // this lane's k-quad within the 16-tile
  const int rowsel = (lane & 15);     // fragment row index
  const int q8 = (lane >> 4) * 8;     // fragment k-quarter offset (in h)

  // rl[s] for this lane's p-row (softmax denominators)
  float rl[16];
#pragma unroll
  for (int s = 0; s < 16; s++)
    rl[s] = rl_ws[(size_t)(bb * 16 + s) * 1024 + p];

  float sum[4] = {0.f, 0.f, 0.f, 0.f}, ssq[4] = {0.f, 0.f, 0.f, 0.f};

  // ---- pass A: accumulate sum / ssq over the 16 heads ----
#pragma unroll
  for (int s = 0; s < 16; s++) {
    size_t base = (size_t)(bb * 16 + s) * 65536;
    const bf16_t* krow = k_ws + base + (size_t)(k_off + rowsel) * 64 + q8;
    const bf16_t* qrow = q_ws + base + (size_t)(p_off + rowsel) * 64 + q8;
    bf16x8_t KA0 = *(const bf16x8_t*)(krow);
    bf16x8_t KA1 = *(const bf16x8_t*)(krow + 32);
    bf16x8_t QB0 = *(const bf16x8_t*)(qrow);
    bf16x8_t QB1 = *(const bf16x8_t*)(qrow + 32);
    f32x4_t z = {0.f, 0.f, 0.f, 0.f};
    f32x4_t sc = __builtin_amdgcn_mfma_f32_16x16x32_bf16(KA0, QB0, z, 0, 0, 0);
    sc = __builtin_amdgcn_mfma_f32_16x16x32_bf16(KA1, QB1, sc, 0, 0, 0);
#pragma unroll
    for (int j = 0; j < 4; j++) {
      int kk = k_off + kloc + j;
      float wv = (kk <= p) ? exp2f(sc[j] * kLog2e) * rl[s] : 0.f;
      sum[j] += wv;
      ssq[j] = fmaf(wv, wv, ssq[j]);
    }
  }

  float mu[4], rstd[4];
#pragma unroll
  for (int j = 0; j < 4; j++) {
    mu[j] = sum[j] * 0.0625f;
    float var = ssq[j] * 0.0625f - mu[j] * mu[j];
    rstd[j] = rsqrtf(var + 1e-5f);
  }

  // ---- pass B: recompute w, apply LN, vectorized f32x4 store ----
#pragma unroll
  for (int s = 0; s < 16; s++) {
    size_t base = (size_t)(bb * 16 + s) * 65536;
    const bf16_t* krow = k_ws + base + (size_t)(k_off + rowsel) * 64 + q8;
    const bf16_t* qrow = q_ws + base + (size_t)(p_off + rowsel) * 64 + q8;
    bf16x8_t KA0 = *(const bf16x8_t*)(krow);
    bf16x8_t KA1 = *(const bf16x8_t*)(krow + 32);
    bf16x8_t QB0 = *(const bf16x8_t*)(qrow);
    bf16x8_t QB1 = *(const bf16x8_t*)(qrow + 32);
    f32x4_t z = {0.f, 0.f, 0.f, 0.f};
    f32x4_t sc = __builtin_amdgcn_mfma_f32_16x16x32_bf16(KA0, QB0, z, 0, 0, 0);
    sc = __builtin_amdgcn_mfma_f32_16x16x32_bf16(KA1, QB1, sc, 0, 0, 0);
    float scl = ln_scale[s], bi = ln_bias[s];
    f32x4_t o;
#pragma unroll
    for (int j = 0; j < 4; j++) {
      int kk = k_off + kloc + j;
      float wv = (kk <= p) ? exp2f(sc[j] * kLog2e) * rl[s] : 0.f;
      o[j] = (wv - mu[j]) * rstd[j] * scl + bi;
    }
    *(f32x4_t*)(out + ((size_t)(bb * 16 + s) * 1024 + p) * 1024 + k_off + kloc) = o;
  }
}

extern "C" void kernel_launch(void* const* d_in, const int* in_sizes, int n_in,
                              void* d_out, int out_size, void* d_ws, size_t ws_size,
                              hipStream_t stream) {
  (void)in_sizes; (void)n_in; (void)out_size; (void)ws_size;
  const float* x        = (const float*)d_in[0];
  // d_in[1] = mask (causal tril; structure hardcoded)
  const float* W        = (const float*)d_in[2];
  const float* bias     = (const float*)d_in[3];
  const float* ln_scale = (const float*)d_in[4];
  const float* ln_bias  = (const float*)d_in[5];
  float* out = (float*)d_out;

  char* ws = (char*)d_ws;
  bf16_t* q_ws = (bf16_t*)ws;                    //  8,388,608 B [b][s][p][h]
  bf16_t* k_ws = (bf16_t*)(ws + 8388608);        //  8,388,608 B
  float*  rl_ws = (float*)(ws + 16777216);       //    262,144 B [b][s][p]
  bf16_t* xb   = (bf16_t*)(ws + 17039360);       //  6,291,456 B [4096][768]
  bf16_t* Wt   = (bf16_t*)(ws + 23330816);       //  3,145,728 B [2048][768]

  k_cvt_x<<<dim3(1536), 256, 0, stream>>>(x, xb);
  k_tr_w <<<dim3(64, 24), 256, 0, stream>>>(W, Wt);
  k_proj <<<dim3(16, 32), 256, 0, stream>>>(xb, Wt, bias, q_ws, k_ws);
  k_sumexp<<<dim3(16, 64), 256, 0, stream>>>(q_ws, k_ws, rl_ws);
  k_final<<<dim3(32, 32, 4), 256, 0, stream>>>(q_ws, k_ws, rl_ws, ln_scale, ln_bias, out);
}

// Round 3
// 182.091 us; speedup vs baseline: 1.3616x; 1.2736x over previous
//
#include <hip/hip_runtime.h>
#include <hip/hip_bf16.h>
#include <math.h>

// WeightsOnlyAttention: qk proj (bf16 MFMA) -> causal softmax over k ->
// LayerNorm across S=16 heads -> out (4,16,1024,1024) fp32.
// B=4 P=1024 E=768 S=16 H=64.

typedef __bf16 bf16_t;
typedef __bf16 bf16x4_t __attribute__((ext_vector_type(4)));
typedef __bf16 bf16x8_t __attribute__((ext_vector_type(8)));
typedef float  f32x4_t  __attribute__((ext_vector_type(4)));
typedef float  f32x16_t __attribute__((ext_vector_type(16)));

#define DEV __device__ __forceinline__
static constexpr float kLog2e = 1.4426950408889634f;

DEV void gload_lds16(const bf16_t* g, bf16_t* l) {
  __builtin_amdgcn_global_load_lds(
      (const __attribute__((address_space(1))) void*)g,
      (__attribute__((address_space(3))) void*)l, 16, 0, 0);
}

// ---------------- x (f32) -> xb (bf16), 4096x768 ----------------
__global__ __launch_bounds__(256) void k_cvt_x(const float* __restrict__ x,
                                               bf16_t* __restrict__ xb) {
  size_t i = ((size_t)blockIdx.x * 256 + threadIdx.x) * 8;
  f32x4_t a = *(const f32x4_t*)(x + i);
  f32x4_t b = *(const f32x4_t*)(x + i + 4);
  bf16x8_t o = {(bf16_t)a[0], (bf16_t)a[1], (bf16_t)a[2], (bf16_t)a[3],
                (bf16_t)b[0], (bf16_t)b[1], (bf16_t)b[2], (bf16_t)b[3]};
  *(bf16x8_t*)(xb + i) = o;
}

// ------------- W [768][2048] f32 -> Wt [2048][768] bf16 -------------
__global__ __launch_bounds__(256) void k_tr_w(const float* __restrict__ W,
                                              bf16_t* __restrict__ Wt) {
  __shared__ float t[32][33];
  int n0 = blockIdx.x * 32, e0 = blockIdx.y * 32;
  int tx = threadIdx.x & 31, ty = threadIdx.x >> 5;  // 32x8
#pragma unroll
  for (int i = 0; i < 4; i++)
    t[ty + 8 * i][tx] = W[(size_t)(e0 + ty + 8 * i) * 2048 + n0 + tx];
  __syncthreads();
#pragma unroll
  for (int i = 0; i < 4; i++)
    Wt[(size_t)(n0 + ty + 8 * i) * 768 + e0 + tx] = (bf16_t)t[tx][ty + 8 * i];
}

// ---------------- projection GEMM: C = xb * Wt^T + bias ----------------
// M=4096 (b,p), N=2048 (qk,s,h), K=768. 128x128 tile, BK=32, 4 waves.
// Epilogue: q = (C+b)*0.125 -> q_ws[b][s][p][h] bf16 ; k -> k_ws.
__global__ __launch_bounds__(256) void k_proj(const bf16_t* __restrict__ xb,
                                              const bf16_t* __restrict__ Wt,
                                              const float* __restrict__ bias,
                                              bf16_t* __restrict__ q_ws,
                                              bf16_t* __restrict__ k_ws) {
  __shared__ bf16_t As[128 * 32];
  __shared__ bf16_t Bs[128 * 32];
  const int tid = threadIdx.x;
  const int lane = tid & 63;
  const int w = tid >> 6;
  const int m0 = blockIdx.y * 128;
  const int n0 = blockIdx.x * 128;
  const int mw = (w >> 1) * 64, nw = (w & 1) * 64;

  f32x4_t zz = {0.f, 0.f, 0.f, 0.f};
  f32x4_t acc[4][4];
#pragma unroll
  for (int mt = 0; mt < 4; mt++)
#pragma unroll
    for (int nt = 0; nt < 4; nt++) acc[mt][nt] = zz;

  for (int k0 = 0; k0 < 768; k0 += 32) {
    __syncthreads();
#pragma unroll
    for (int i = 0; i < 2; i++) {
      int cbase = w * 128 + i * 64;     // 16B-chunk base for this wave-instr
      int c = cbase + lane;             // chunk: row = c>>2, 8-elem quarter = c&3
      int r = c >> 2, q8 = c & 3;
      gload_lds16(xb + (size_t)(m0 + r) * 768 + k0 + q8 * 8, As + cbase * 8);
      gload_lds16(Wt + (size_t)(n0 + r) * 768 + k0 + q8 * 8, Bs + cbase * 8);
    }
    __syncthreads();
    bf16x8_t a[4], b[4];
#pragma unroll
    for (int mt = 0; mt < 4; mt++)
      a[mt] = *(const bf16x8_t*)(As + (mw + mt * 16 + (lane & 15)) * 32 + (lane >> 4) * 8);
#pragma unroll
    for (int nt = 0; nt < 4; nt++)
      b[nt] = *(const bf16x8_t*)(Bs + (nw + nt * 16 + (lane & 15)) * 32 + (lane >> 4) * 8);
#pragma unroll
    for (int mt = 0; mt < 4; mt++)
#pragma unroll
      for (int nt = 0; nt < 4; nt++)
        acc[mt][nt] = __builtin_amdgcn_mfma_f32_16x16x32_bf16(a[mt], b[nt], acc[mt][nt], 0, 0, 0);
  }

#pragma unroll
  for (int mt = 0; mt < 4; mt++) {
    int row0 = mw + mt * 16 + (lane >> 4) * 4;
#pragma unroll
    for (int nt = 0; nt < 4; nt++) {
      int col = nw + nt * 16 + (lane & 15);
      int n = n0 + col;
      int s = (n >> 6) & 15, h = n & 63, qk = n >> 10;
      float bv = bias[n];
#pragma unroll
      for (int j = 0; j < 4; j++) {
        int m = m0 + row0 + j;
        int bi = m >> 10, p = m & 1023;
        float v = acc[mt][nt][j] + bv;
        size_t off = ((size_t)(bi * 16 + s) * 1024 + p) * 64 + h;
        if (qk == 0) q_ws[off] = (bf16_t)(v * 0.125f);
        else         k_ws[off] = (bf16_t)v;
      }
    }
  }
}

// ---------------- rl[b][s][p] = 1 / sum_{k<=p} exp(score) ----------------
// grid (16 pblocks, 64 bs), 4 waves x 16 rows. Scores via 16x16x32 MFMA.
__global__ __launch_bounds__(256) void k_sumexp(const bf16_t* __restrict__ q_ws,
                                                const bf16_t* __restrict__ k_ws,
                                                float* __restrict__ rl_ws) {
  const int tid = threadIdx.x, lane = tid & 63, w = tid >> 6;
  const int bs = blockIdx.y;
  const int r0 = blockIdx.x * 64 + w * 16;
  const size_t base = (size_t)bs * 65536;  // 1024*64

  const bf16_t* qrow = q_ws + base + (size_t)(r0 + (lane & 15)) * 64 + (lane >> 4) * 8;
  bf16x8_t A0 = *(const bf16x8_t*)(qrow);
  bf16x8_t A1 = *(const bf16x8_t*)(qrow + 32);

  float sum[4] = {0.f, 0.f, 0.f, 0.f};
  const int ktmax = (r0 + 15) >> 4;
  for (int kt = 0; kt <= ktmax; kt++) {
    const bf16_t* krow = k_ws + base + (size_t)(kt * 16 + (lane & 15)) * 64 + (lane >> 4) * 8;
    bf16x8_t B0 = *(const bf16x8_t*)(krow);
    bf16x8_t B1 = *(const bf16x8_t*)(krow + 32);
    f32x4_t z = {0.f, 0.f, 0.f, 0.f};
    f32x4_t sc = __builtin_amdgcn_mfma_f32_16x16x32_bf16(A0, B0, z, 0, 0, 0);
    sc = __builtin_amdgcn_mfma_f32_16x16x32_bf16(A1, B1, sc, 0, 0, 0);
    int col = kt * 16 + (lane & 15);
#pragma unroll
    for (int j = 0; j < 4; j++) {
      int row = r0 + (lane >> 4) * 4 + j;
      float e = (col <= row) ? exp2f(sc[j] * kLog2e) : 0.f;
      sum[j] += e;
    }
  }
#pragma unroll
  for (int j = 0; j < 4; j++)
#pragma unroll
    for (int msk = 1; msk < 16; msk <<= 1) sum[j] += __shfl_xor(sum[j], msk, 64);
  if ((lane & 15) == 0) {
#pragma unroll
    for (int j = 0; j < 4; j++)
      rl_ws[(size_t)bs * 1024 + r0 + (lane >> 4) * 4 + j] = 1.0f / sum[j];
  }
}

// ------- final: recompute scores, w=exp*rl, LN over 16 heads, write -------
// 1D grid 4096 blocks (XCD-swizzled), decode (bb,pb,kb); 4 waves, each wave
// owns 4 HEADS of the full 32x32 (p,k) tile via mfma_f32_32x32x16_bf16
// (A=K, B=Q swapped: col=lane&31 -> p, reg rows -> k; reg quads = 4
// consecutive k -> f32x4 stores). q/k read ONCE per (s,tile); w lives in
// the 64 accumulator VGPRs (single pass). Head-reduce via 32KB LDS.
__global__ __launch_bounds__(256, 2) void k_final(const bf16_t* __restrict__ q_ws,
                                                  const bf16_t* __restrict__ k_ws,
                                                  const float* __restrict__ rl_ws,
                                                  const float* __restrict__ ln_scale,
                                                  const float* __restrict__ ln_bias,
                                                  float* __restrict__ out) {
  const int tid = threadIdx.x, lane = tid & 63, w = tid >> 6;
  const int raw = blockIdx.x;
  const int swz = (raw & 7) * 512 + (raw >> 3);  // XCD-contiguous chunks
  const int bb = swz >> 10, pb = (swz >> 5) & 31, kb = swz & 31;
  const int pbase = pb * 32, kbase = kb * 32;

  if (kbase > pbase + 31) {  // fully masked: w=0 for all heads -> out = ln_bias
    int pl = tid >> 3, kq = (tid & 7) * 4;
#pragma unroll
    for (int s = 0; s < 16; s++) {
      float bv = ln_bias[s];
      f32x4_t v = {bv, bv, bv, bv};
      *(f32x4_t*)(out + ((size_t)(bb * 16 + s) * 1024 + pbase + pl) * 1024 + kbase + kq) = v;
    }
    return;
  }

  __shared__ float red_sum[16][4][64];
  __shared__ float red_ssq[16][4][64];

  const int col = lane & 31, hi = lane >> 5;
  const int p = pbase + col;

  f32x16_t c[4];
#pragma unroll
  for (int sp = 0; sp < 4; sp++)
#pragma unroll
    for (int j = 0; j < 16; j++) c[sp][j] = 0.f;

  // score tiles for this wave's 4 heads
#pragma unroll
  for (int sp = 0; sp < 4; sp++) {
    int s = w * 4 + sp;
    size_t base = (size_t)(bb * 16 + s) * 65536;
    const bf16_t* krow = k_ws + base + (size_t)(kbase + col) * 64 + hi * 8;
    const bf16_t* qrow = q_ws + base + (size_t)(p) * 64 + hi * 8;
    bf16x8_t ka[4], qb[4];
#pragma unroll
    for (int t = 0; t < 4; t++) {
      ka[t] = *(const bf16x8_t*)(krow + t * 16);
      qb[t] = *(const bf16x8_t*)(qrow + t * 16);
    }
#pragma unroll
    for (int t = 0; t < 4; t++)
      c[sp] = __builtin_amdgcn_mfma_f32_32x32x16_bf16(ka[t], qb[t], c[sp], 0, 0, 0);
  }

  float rl[4];
#pragma unroll
  for (int sp = 0; sp < 4; sp++)
    rl[sp] = rl_ws[(size_t)(bb * 16 + w * 4 + sp) * 1024 + p];

  // w = exp(score)*rl (causal), overwrite acc in place; per-wave partial stats
  float sum_p[16], ssq_p[16];
#pragma unroll
  for (int j = 0; j < 16; j++) { sum_p[j] = 0.f; ssq_p[j] = 0.f; }
#pragma unroll
  for (int sp = 0; sp < 4; sp++) {
#pragma unroll
    for (int j = 0; j < 16; j++) {
      int kk = kbase + (j & 3) + 8 * (j >> 2) + 4 * hi;
      float wv = (kk <= p) ? exp2f(c[sp][j] * kLog2e) * rl[sp] : 0.f;
      c[sp][j] = wv;
      sum_p[j] += wv;
      ssq_p[j] = fmaf(wv, wv, ssq_p[j]);
    }
  }

#pragma unroll
  for (int j = 0; j < 16; j++) {
    red_sum[j][w][lane] = sum_p[j];
    red_ssq[j][w][lane] = ssq_p[j];
  }
  __syncthreads();

  float mu[16], rs[16];
#pragma unroll
  for (int j = 0; j < 16; j++) {
    float s4 = red_sum[j][0][lane] + red_sum[j][1][lane] +
               red_sum[j][2][lane] + red_sum[j][3][lane];
    float q4 = red_ssq[j][0][lane] + red_ssq[j][1][lane] +
               red_ssq[j][2][lane] + red_ssq[j][3][lane];
    float m = s4 * 0.0625f;
    mu[j] = m;
    rs[j] = rsqrtf(q4 * 0.0625f - m * m + 1e-5f);
  }

#pragma unroll
  for (int sp = 0; sp < 4; sp++) {
    int s = w * 4 + sp;
    float scl = ln_scale[s], bi = ln_bias[s];
    size_t ob = ((size_t)(bb * 16 + s) * 1024 + p) * 1024 + kbase;
#pragma unroll
    for (int qd = 0; qd < 4; qd++) {
      f32x4_t o;
#pragma unroll
      for (int e = 0; e < 4; e++) {
        int j = qd * 4 + e;
        o[e] = (c[sp][j] - mu[j]) * rs[j] * scl + bi;
      }
      *(f32x4_t*)(out + ob + qd * 8 + hi * 4) = o;
    }
  }
}

extern "C" void kernel_launch(void* const* d_in, const int* in_sizes, int n_in,
                              void* d_out, int out_size, void* d_ws, size_t ws_size,
                              hipStream_t stream) {
  (void)in_sizes; (void)n_in; (void)out_size; (void)ws_size;
  const float* x        = (const float*)d_in[0];
  // d_in[1] = mask (causal tril; structure hardcoded)
  const float* W        = (const float*)d_in[2];
  const float* bias     = (const float*)d_in[3];
  const float* ln_scale = (const float*)d_in[4];
  const float* ln_bias  = (const float*)d_in[5];
  float* out = (float*)d_out;

  char* ws = (char*)d_ws;
  bf16_t* q_ws = (bf16_t*)ws;                    //  8,388,608 B [b][s][p][h]
  bf16_t* k_ws = (bf16_t*)(ws + 8388608);        //  8,388,608 B
  float*  rl_ws = (float*)(ws + 16777216);       //    262,144 B [b][s][p]
  bf16_t* xb   = (bf16_t*)(ws + 17039360);       //  6,291,456 B [4096][768]
  bf16_t* Wt   = (bf16_t*)(ws + 23330816);       //  3,145,728 B [2048][768]

  k_cvt_x<<<dim3(1536), 256, 0, stream>>>(x, xb);
  k_tr_w <<<dim3(64, 24), 256, 0, stream>>>(W, Wt);
  k_proj <<<dim3(16, 32), 256, 0, stream>>>(xb, Wt, bias, q_ws, k_ws);
  k_sumexp<<<dim3(16, 64), 256, 0, stream>>>(q_ws, k_ws, rl_ws);
  k_final<<<dim3(4096), 256, 0, stream>>>(q_ws, k_ws, rl_ws, ln_scale, ln_bias, out);
}

// Round 4
// 172.229 us; speedup vs baseline: 1.4395x; 1.0573x over previous
//
#include <hip/hip_runtime.h>
#include <hip/hip_bf16.h>
#include <math.h>

// WeightsOnlyAttention: qk proj (bf16 MFMA) -> causal softmax over k ->
// LayerNorm across S=16 heads -> out (4,16,1024,1024) fp32.
// B=4 P=1024 E=768 S=16 H=64.

typedef __bf16 bf16_t;
typedef __bf16 bf16x4_t __attribute__((ext_vector_type(4)));
typedef __bf16 bf16x8_t __attribute__((ext_vector_type(8)));
typedef float  f32x4_t  __attribute__((ext_vector_type(4)));
typedef float  f32x16_t __attribute__((ext_vector_type(16)));

#define DEV __device__ __forceinline__
static constexpr float kLog2e = 1.4426950408889634f;

DEV void gload_lds16(const bf16_t* g, bf16_t* l) {
  __builtin_amdgcn_global_load_lds(
      (const __attribute__((address_space(1))) void*)g,
      (__attribute__((address_space(3))) void*)l, 16, 0, 0);
}

// ---------------- x (f32) -> xb (bf16), 4096x768 ----------------
__global__ __launch_bounds__(256) void k_cvt_x(const float* __restrict__ x,
                                               bf16_t* __restrict__ xb) {
  size_t i = ((size_t)blockIdx.x * 256 + threadIdx.x) * 8;
  f32x4_t a = *(const f32x4_t*)(x + i);
  f32x4_t b = *(const f32x4_t*)(x + i + 4);
  bf16x8_t o = {(bf16_t)a[0], (bf16_t)a[1], (bf16_t)a[2], (bf16_t)a[3],
                (bf16_t)b[0], (bf16_t)b[1], (bf16_t)b[2], (bf16_t)b[3]};
  *(bf16x8_t*)(xb + i) = o;
}

// ------------- W [768][2048] f32 -> Wt [2048][768] bf16 -------------
__global__ __launch_bounds__(256) void k_tr_w(const float* __restrict__ W,
                                              bf16_t* __restrict__ Wt) {
  __shared__ float t[32][33];
  int n0 = blockIdx.x * 32, e0 = blockIdx.y * 32;
  int tx = threadIdx.x & 31, ty = threadIdx.x >> 5;  // 32x8
#pragma unroll
  for (int i = 0; i < 4; i++)
    t[ty + 8 * i][tx] = W[(size_t)(e0 + ty + 8 * i) * 2048 + n0 + tx];
  __syncthreads();
#pragma unroll
  for (int i = 0; i < 4; i++)
    Wt[(size_t)(n0 + ty + 8 * i) * 768 + e0 + tx] = (bf16_t)t[tx][ty + 8 * i];
}

// ---------------- projection GEMM: C = xb * Wt^T + bias ----------------
// M=4096 (b,p), N=2048 (qk,s,h), K=768. 128x128 tile, BK=32, 4 waves.
// Epilogue: q = (C+b)*0.125 -> q_ws[b][s][p][h] bf16 ; k -> k_ws.
__global__ __launch_bounds__(256) void k_proj(const bf16_t* __restrict__ xb,
                                              const bf16_t* __restrict__ Wt,
                                              const float* __restrict__ bias,
                                              bf16_t* __restrict__ q_ws,
                                              bf16_t* __restrict__ k_ws) {
  __shared__ bf16_t As[128 * 32];
  __shared__ bf16_t Bs[128 * 32];
  const int tid = threadIdx.x;
  const int lane = tid & 63;
  const int w = tid >> 6;
  const int m0 = blockIdx.y * 128;
  const int n0 = blockIdx.x * 128;
  const int mw = (w >> 1) * 64, nw = (w & 1) * 64;

  f32x4_t zz = {0.f, 0.f, 0.f, 0.f};
  f32x4_t acc[4][4];
#pragma unroll
  for (int mt = 0; mt < 4; mt++)
#pragma unroll
    for (int nt = 0; nt < 4; nt++) acc[mt][nt] = zz;

  for (int k0 = 0; k0 < 768; k0 += 32) {
    __syncthreads();
#pragma unroll
    for (int i = 0; i < 2; i++) {
      int cbase = w * 128 + i * 64;     // 16B-chunk base for this wave-instr
      int c = cbase + lane;             // chunk: row = c>>2, 8-elem quarter = c&3
      int r = c >> 2, q8 = c & 3;
      gload_lds16(xb + (size_t)(m0 + r) * 768 + k0 + q8 * 8, As + cbase * 8);
      gload_lds16(Wt + (size_t)(n0 + r) * 768 + k0 + q8 * 8, Bs + cbase * 8);
    }
    __syncthreads();
    bf16x8_t a[4], b[4];
#pragma unroll
    for (int mt = 0; mt < 4; mt++)
      a[mt] = *(const bf16x8_t*)(As + (mw + mt * 16 + (lane & 15)) * 32 + (lane >> 4) * 8);
#pragma unroll
    for (int nt = 0; nt < 4; nt++)
      b[nt] = *(const bf16x8_t*)(Bs + (nw + nt * 16 + (lane & 15)) * 32 + (lane >> 4) * 8);
#pragma unroll
    for (int mt = 0; mt < 4; mt++)
#pragma unroll
      for (int nt = 0; nt < 4; nt++)
        acc[mt][nt] = __builtin_amdgcn_mfma_f32_16x16x32_bf16(a[mt], b[nt], acc[mt][nt], 0, 0, 0);
  }

#pragma unroll
  for (int mt = 0; mt < 4; mt++) {
    int row0 = mw + mt * 16 + (lane >> 4) * 4;
#pragma unroll
    for (int nt = 0; nt < 4; nt++) {
      int col = nw + nt * 16 + (lane & 15);
      int n = n0 + col;
      int s = (n >> 6) & 15, h = n & 63, qk = n >> 10;
      float bv = bias[n];
#pragma unroll
      for (int j = 0; j < 4; j++) {
        int m = m0 + row0 + j;
        int bi = m >> 10, p = m & 1023;
        float v = acc[mt][nt][j] + bv;
        size_t off = ((size_t)(bi * 16 + s) * 1024 + p) * 64 + h;
        if (qk == 0) q_ws[off] = (bf16_t)(v * 0.125f);
        else         k_ws[off] = (bf16_t)v;
      }
    }
  }
}

// ---------------- rl[b][s][p] = 1 / sum_{k<=p} exp(score) ----------------
// grid (16 pblocks, 64 bs), 4 waves x 16 rows. Scores via 16x16x32 MFMA.
__global__ __launch_bounds__(256) void k_sumexp(const bf16_t* __restrict__ q_ws,
                                                const bf16_t* __restrict__ k_ws,
                                                float* __restrict__ rl_ws) {
  const int tid = threadIdx.x, lane = tid & 63, w = tid >> 6;
  const int bs = blockIdx.y;
  const int r0 = blockIdx.x * 64 + w * 16;
  const size_t base = (size_t)bs * 65536;  // 1024*64

  const bf16_t* qrow = q_ws + base + (size_t)(r0 + (lane & 15)) * 64 + (lane >> 4) * 8;
  bf16x8_t A0 = *(const bf16x8_t*)(qrow);
  bf16x8_t A1 = *(const bf16x8_t*)(qrow + 32);

  float sum[4] = {0.f, 0.f, 0.f, 0.f};
  const int ktmax = (r0 + 15) >> 4;
  for (int kt = 0; kt <= ktmax; kt++) {
    const bf16_t* krow = k_ws + base + (size_t)(kt * 16 + (lane & 15)) * 64 + (lane >> 4) * 8;
    bf16x8_t B0 = *(const bf16x8_t*)(krow);
    bf16x8_t B1 = *(const bf16x8_t*)(krow + 32);
    f32x4_t z = {0.f, 0.f, 0.f, 0.f};
    f32x4_t sc = __builtin_amdgcn_mfma_f32_16x16x32_bf16(A0, B0, z, 0, 0, 0);
    sc = __builtin_amdgcn_mfma_f32_16x16x32_bf16(A1, B1, sc, 0, 0, 0);
    int col = kt * 16 + (lane & 15);
#pragma unroll
    for (int j = 0; j < 4; j++) {
      int row = r0 + (lane >> 4) * 4 + j;
      float e = (col <= row) ? exp2f(sc[j] * kLog2e) : 0.f;
      sum[j] += e;
    }
  }
#pragma unroll
  for (int j = 0; j < 4; j++)
#pragma unroll
    for (int msk = 1; msk < 16; msk <<= 1) sum[j] += __shfl_xor(sum[j], msk, 64);
  if ((lane & 15) == 0) {
#pragma unroll
    for (int j = 0; j < 4; j++)
      rl_ws[(size_t)bs * 1024 + r0 + (lane >> 4) * 4 + j] = 1.0f / sum[j];
  }
}

// ------- final: recompute scores, w=exp*rl, LN over 16 heads, write -------
// 1D grid 4096 blocks (XCD-swizzled), decode (bb,pb,kb); 4 waves, each wave
// owns 4 HEADS of the full 32x32 (p,k) tile via mfma_f32_32x32x16_bf16.
// UNSWAPPED operands (A=Q rows=p, B=K rows=k): C col=lane&31 -> k (lane-
// contiguous!), reg rows -> p. Scalar dword stores: each instr writes 2
// fully-dense 128B row segments (vs 32x16B scatter before) -> 4x fewer L2
// write transactions. rl staged in LDS (per-reg p-rows need broadcast).
__global__ __launch_bounds__(256, 2) void k_final(const bf16_t* __restrict__ q_ws,
                                                  const bf16_t* __restrict__ k_ws,
                                                  const float* __restrict__ rl_ws,
                                                  const float* __restrict__ ln_scale,
                                                  const float* __restrict__ ln_bias,
                                                  float* __restrict__ out) {
  const int tid = threadIdx.x, lane = tid & 63, w = tid >> 6;
  const int raw = blockIdx.x;
  const int swz = (raw & 7) * 512 + (raw >> 3);  // XCD-contiguous chunks
  const int bb = swz >> 10, pb = (swz >> 5) & 31, kb = swz & 31;
  const int pbase = pb * 32, kbase = kb * 32;

  if (kbase > pbase + 31) {  // fully masked: w=0 for all heads -> out = ln_bias
    int pl = tid >> 3, kq = (tid & 7) * 4;
#pragma unroll
    for (int s = 0; s < 16; s++) {
      float bv = ln_bias[s];
      f32x4_t v = {bv, bv, bv, bv};
      *(f32x4_t*)(out + ((size_t)(bb * 16 + s) * 1024 + pbase + pl) * 1024 + kbase + kq) = v;
    }
    return;
  }

  __shared__ float red_sum[16][4][64];
  __shared__ float red_ssq[16][4][64];
  __shared__ float rl_lds[16][32];

  const int col = lane & 31, hi = lane >> 5;
  const int kcol = kbase + col;

  // cooperative stage of rl (16 heads x 32 p-rows) into LDS
#pragma unroll
  for (int r = 0; r < 2; r++) {
    int idx = tid + r * 256;
    int s = idx >> 5, pr = idx & 31;
    rl_lds[s][pr] = rl_ws[(size_t)(bb * 16 + s) * 1024 + pbase + pr];
  }

  f32x16_t c[4];
#pragma unroll
  for (int sp = 0; sp < 4; sp++)
#pragma unroll
    for (int j = 0; j < 16; j++) c[sp][j] = 0.f;

  // score tiles for this wave's 4 heads: A=Q (rows=p), B=K (rows=k)
#pragma unroll
  for (int sp = 0; sp < 4; sp++) {
    int s = w * 4 + sp;
    size_t base = (size_t)(bb * 16 + s) * 65536;
    const bf16_t* qrow = q_ws + base + (size_t)(pbase + col) * 64 + hi * 8;
    const bf16_t* krow = k_ws + base + (size_t)kcol * 64 + hi * 8;
    bf16x8_t qa[4], kv[4];
#pragma unroll
    for (int t = 0; t < 4; t++) {
      qa[t] = *(const bf16x8_t*)(qrow + t * 16);
      kv[t] = *(const bf16x8_t*)(krow + t * 16);
    }
#pragma unroll
    for (int t = 0; t < 4; t++)
      c[sp] = __builtin_amdgcn_mfma_f32_32x32x16_bf16(qa[t], kv[t], c[sp], 0, 0, 0);
  }

  __syncthreads();  // rl_lds ready

  // w = exp(score)*rl (causal), overwrite acc in place; per-wave partial stats
  float sum_p[16], ssq_p[16];
#pragma unroll
  for (int j = 0; j < 16; j++) { sum_p[j] = 0.f; ssq_p[j] = 0.f; }
#pragma unroll
  for (int sp = 0; sp < 4; sp++) {
    int s = w * 4 + sp;
#pragma unroll
    for (int j = 0; j < 16; j++) {
      int prl = (j & 3) + 8 * (j >> 2) + 4 * hi;   // p-row within tile
      float wv = (kcol <= pbase + prl) ? exp2f(c[sp][j] * kLog2e) * rl_lds[s][prl] : 0.f;
      c[sp][j] = wv;
      sum_p[j] += wv;
      ssq_p[j] = fmaf(wv, wv, ssq_p[j]);
    }
  }

#pragma unroll
  for (int j = 0; j < 16; j++) {
    red_sum[j][w][lane] = sum_p[j];
    red_ssq[j][w][lane] = ssq_p[j];
  }
  __syncthreads();

  float mu[16], rs[16];
#pragma unroll
  for (int j = 0; j < 16; j++) {
    float s4 = red_sum[j][0][lane] + red_sum[j][1][lane] +
               red_sum[j][2][lane] + red_sum[j][3][lane];
    float q4 = red_ssq[j][0][lane] + red_ssq[j][1][lane] +
               red_ssq[j][2][lane] + red_ssq[j][3][lane];
    float m = s4 * 0.0625f;
    mu[j] = m;
    rs[j] = rsqrtf(q4 * 0.0625f - m * m + 1e-5f);
  }

  // stores: scalar dwords; lanes 0-31 cover 128B of row prl(hi=0),
  // lanes 32-63 row prl+4 -> 2 dense 128B segments per instruction.
#pragma unroll
  for (int sp = 0; sp < 4; sp++) {
    int s = w * 4 + sp;
    float scl = ln_scale[s], bi = ln_bias[s];
    size_t hb = ((size_t)(bb * 16 + s) * 1024 + pbase) * 1024 + kbase;
#pragma unroll
    for (int j = 0; j < 16; j++) {
      int prl = (j & 3) + 8 * (j >> 2) + 4 * hi;
      out[hb + (size_t)prl * 1024 + col] = (c[sp][j] - mu[j]) * rs[j] * scl + bi;
    }
  }
}

extern "C" void kernel_launch(void* const* d_in, const int* in_sizes, int n_in,
                              void* d_out, int out_size, void* d_ws, size_t ws_size,
                              hipStream_t stream) {
  (void)in_sizes; (void)n_in; (void)out_size; (void)ws_size;
  const float* x        = (const float*)d_in[0];
  // d_in[1] = mask (causal tril; structure hardcoded)
  const float* W        = (const float*)d_in[2];
  const float* bias     = (const float*)d_in[3];
  const float* ln_scale = (const float*)d_in[4];
  const float* ln_bias  = (const float*)d_in[5];
  float* out = (float*)d_out;

  char* ws = (char*)d_ws;
  bf16_t* q_ws = (bf16_t*)ws;                    //  8,388,608 B [b][s][p][h]
  bf16_t* k_ws = (bf16_t*)(ws + 8388608);        //  8,388,608 B
  float*  rl_ws = (float*)(ws + 16777216);       //    262,144 B [b][s][p]
  bf16_t* xb   = (bf16_t*)(ws + 17039360);       //  6,291,456 B [4096][768]
  bf16_t* Wt   = (bf16_t*)(ws + 23330816);       //  3,145,728 B [2048][768]

  k_cvt_x<<<dim3(1536), 256, 0, stream>>>(x, xb);
  k_tr_w <<<dim3(64, 24), 256, 0, stream>>>(W, Wt);
  k_proj <<<dim3(16, 32), 256, 0, stream>>>(xb, Wt, bias, q_ws, k_ws);
  k_sumexp<<<dim3(16, 64), 256, 0, stream>>>(q_ws, k_ws, rl_ws);
  k_final<<<dim3(4096), 256, 0, stream>>>(q_ws, k_ws, rl_ws, ln_scale, ln_bias, out);
}

// Round 5
// 165.319 us; speedup vs baseline: 1.4997x; 1.0418x over previous
//
#include <hip/hip_runtime.h>
#include <hip/hip_bf16.h>
#include <math.h>

// WeightsOnlyAttention: qk proj (bf16 MFMA) -> causal softmax over k ->
// LayerNorm across S=16 heads -> out (4,16,1024,1024) fp32.
// B=4 P=1024 E=768 S=16 H=64.

typedef __bf16 bf16_t;
typedef __bf16 bf16x4_t __attribute__((ext_vector_type(4)));
typedef __bf16 bf16x8_t __attribute__((ext_vector_type(8)));
typedef float  f32x4_t  __attribute__((ext_vector_type(4)));
typedef float  f32x16_t __attribute__((ext_vector_type(16)));

#define DEV __device__ __forceinline__
static constexpr float kLog2e = 1.4426950408889634f;

DEV void gload_lds16(const bf16_t* g, bf16_t* l) {
  __builtin_amdgcn_global_load_lds(
      (const __attribute__((address_space(1))) void*)g,
      (__attribute__((address_space(3))) void*)l, 16, 0, 0);
}

// ---------------- x (f32) -> xb (bf16), 4096x768 ----------------
__global__ __launch_bounds__(256) void k_cvt_x(const float* __restrict__ x,
                                               bf16_t* __restrict__ xb) {
  size_t i = ((size_t)blockIdx.x * 256 + threadIdx.x) * 8;
  f32x4_t a = *(const f32x4_t*)(x + i);
  f32x4_t b = *(const f32x4_t*)(x + i + 4);
  bf16x8_t o = {(bf16_t)a[0], (bf16_t)a[1], (bf16_t)a[2], (bf16_t)a[3],
                (bf16_t)b[0], (bf16_t)b[1], (bf16_t)b[2], (bf16_t)b[3]};
  *(bf16x8_t*)(xb + i) = o;
}

// ------------- W [768][2048] f32 -> Wt [2048][768] bf16 -------------
__global__ __launch_bounds__(256) void k_tr_w(const float* __restrict__ W,
                                              bf16_t* __restrict__ Wt) {
  __shared__ float t[32][33];
  int n0 = blockIdx.x * 32, e0 = blockIdx.y * 32;
  int tx = threadIdx.x & 31, ty = threadIdx.x >> 5;  // 32x8
#pragma unroll
  for (int i = 0; i < 4; i++)
    t[ty + 8 * i][tx] = W[(size_t)(e0 + ty + 8 * i) * 2048 + n0 + tx];
  __syncthreads();
#pragma unroll
  for (int i = 0; i < 4; i++)
    Wt[(size_t)(n0 + ty + 8 * i) * 768 + e0 + tx] = (bf16_t)t[tx][ty + 8 * i];
}

// ---------------- projection GEMM: C = xb * Wt^T + bias ----------------
// M=4096 (b,p), N=2048 (qk,s,h), K=768. 128x128 tile, BK=32, 4 waves.
// Epilogue: q = (C+b)*0.125 -> q_ws[b][s][p][h] bf16 ; k -> k_ws.
__global__ __launch_bounds__(256) void k_proj(const bf16_t* __restrict__ xb,
                                              const bf16_t* __restrict__ Wt,
                                              const float* __restrict__ bias,
                                              bf16_t* __restrict__ q_ws,
                                              bf16_t* __restrict__ k_ws) {
  __shared__ bf16_t As[128 * 32];
  __shared__ bf16_t Bs[128 * 32];
  const int tid = threadIdx.x;
  const int lane = tid & 63;
  const int w = tid >> 6;
  const int m0 = blockIdx.y * 128;
  const int n0 = blockIdx.x * 128;
  const int mw = (w >> 1) * 64, nw = (w & 1) * 64;

  f32x4_t zz = {0.f, 0.f, 0.f, 0.f};
  f32x4_t acc[4][4];
#pragma unroll
  for (int mt = 0; mt < 4; mt++)
#pragma unroll
    for (int nt = 0; nt < 4; nt++) acc[mt][nt] = zz;

  for (int k0 = 0; k0 < 768; k0 += 32) {
    __syncthreads();
#pragma unroll
    for (int i = 0; i < 2; i++) {
      int cbase = w * 128 + i * 64;     // 16B-chunk base for this wave-instr
      int c = cbase + lane;             // chunk: row = c>>2, 8-elem quarter = c&3
      int r = c >> 2, q8 = c & 3;
      gload_lds16(xb + (size_t)(m0 + r) * 768 + k0 + q8 * 8, As + cbase * 8);
      gload_lds16(Wt + (size_t)(n0 + r) * 768 + k0 + q8 * 8, Bs + cbase * 8);
    }
    __syncthreads();
    bf16x8_t a[4], b[4];
#pragma unroll
    for (int mt = 0; mt < 4; mt++)
      a[mt] = *(const bf16x8_t*)(As + (mw + mt * 16 + (lane & 15)) * 32 + (lane >> 4) * 8);
#pragma unroll
    for (int nt = 0; nt < 4; nt++)
      b[nt] = *(const bf16x8_t*)(Bs + (nw + nt * 16 + (lane & 15)) * 32 + (lane >> 4) * 8);
#pragma unroll
    for (int mt = 0; mt < 4; mt++)
#pragma unroll
      for (int nt = 0; nt < 4; nt++)
        acc[mt][nt] = __builtin_amdgcn_mfma_f32_16x16x32_bf16(a[mt], b[nt], acc[mt][nt], 0, 0, 0);
  }

#pragma unroll
  for (int mt = 0; mt < 4; mt++) {
    int row0 = mw + mt * 16 + (lane >> 4) * 4;
#pragma unroll
    for (int nt = 0; nt < 4; nt++) {
      int col = nw + nt * 16 + (lane & 15);
      int n = n0 + col;
      int s = (n >> 6) & 15, h = n & 63, qk = n >> 10;
      float bv = bias[n];
#pragma unroll
      for (int j = 0; j < 4; j++) {
        int m = m0 + row0 + j;
        int bi = m >> 10, p = m & 1023;
        float v = acc[mt][nt][j] + bv;
        size_t off = ((size_t)(bi * 16 + s) * 1024 + p) * 64 + h;
        if (qk == 0) q_ws[off] = (bf16_t)(v * 0.125f);
        else         k_ws[off] = (bf16_t)v;
      }
    }
  }
}

// ---------------- rl[b][s][p] = 1 / sum_{k<=p} exp(score) ----------------
// grid (16 pblocks, 64 bs), 4 waves x 16 rows. Scores via 16x16x32 MFMA.
__global__ __launch_bounds__(256) void k_sumexp(const bf16_t* __restrict__ q_ws,
                                                const bf16_t* __restrict__ k_ws,
                                                float* __restrict__ rl_ws) {
  const int tid = threadIdx.x, lane = tid & 63, w = tid >> 6;
  const int bs = blockIdx.y;
  const int r0 = blockIdx.x * 64 + w * 16;
  const size_t base = (size_t)bs * 65536;  // 1024*64

  const bf16_t* qrow = q_ws + base + (size_t)(r0 + (lane & 15)) * 64 + (lane >> 4) * 8;
  bf16x8_t A0 = *(const bf16x8_t*)(qrow);
  bf16x8_t A1 = *(const bf16x8_t*)(qrow + 32);

  float sum[4] = {0.f, 0.f, 0.f, 0.f};
  const int ktmax = (r0 + 15) >> 4;
  for (int kt = 0; kt <= ktmax; kt++) {
    const bf16_t* krow = k_ws + base + (size_t)(kt * 16 + (lane & 15)) * 64 + (lane >> 4) * 8;
    bf16x8_t B0 = *(const bf16x8_t*)(krow);
    bf16x8_t B1 = *(const bf16x8_t*)(krow + 32);
    f32x4_t z = {0.f, 0.f, 0.f, 0.f};
    f32x4_t sc = __builtin_amdgcn_mfma_f32_16x16x32_bf16(A0, B0, z, 0, 0, 0);
    sc = __builtin_amdgcn_mfma_f32_16x16x32_bf16(A1, B1, sc, 0, 0, 0);
    int col = kt * 16 + (lane & 15);
#pragma unroll
    for (int j = 0; j < 4; j++) {
      int row = r0 + (lane >> 4) * 4 + j;
      float e = (col <= row) ? exp2f(sc[j] * kLog2e) : 0.f;
      sum[j] += e;
    }
  }
#pragma unroll
  for (int j = 0; j < 4; j++)
#pragma unroll
    for (int msk = 1; msk < 16; msk <<= 1) sum[j] += __shfl_xor(sum[j], msk, 64);
  if ((lane & 15) == 0) {
#pragma unroll
    for (int j = 0; j < 4; j++)
      rl_ws[(size_t)bs * 1024 + r0 + (lane >> 4) * 4 + j] = 1.0f / sum[j];
  }
}

// ------- final: recompute scores, w=exp*rl, LN over 16 heads, write -------
// 1D grid 4096 blocks (XCD-swizzled) x 512 threads; 8 waves x 2 heads of the
// 32x32 (p,k) tile via mfma_f32_32x32x16_bf16 (A=Q rows=p, B=K rows=k ->
// C col=lane&31 = k, lane-contiguous stores). Per-thread state halved vs
// 4-head variant -> <=128 VGPR (launch_bounds 512,4) -> 16 waves/CU.
// Cross-wave head-reduce: two-stage cell-major LDS (f32x4 reads), ~4x less
// LDS traffic than naive [j][w][lane]. All output stores nontemporal (out is
// write-once; keep L2 for q/k).
__global__ __launch_bounds__(512, 4) void k_final(const bf16_t* __restrict__ q_ws,
                                                  const bf16_t* __restrict__ k_ws,
                                                  const float* __restrict__ rl_ws,
                                                  const float* __restrict__ ln_scale,
                                                  const float* __restrict__ ln_bias,
                                                  float* __restrict__ out) {
  const int tid = threadIdx.x, lane = tid & 63, w = tid >> 6;  // w in [0,8)
  const int raw = blockIdx.x;
  const int swz = (raw & 7) * 512 + (raw >> 3);  // XCD-contiguous chunks
  const int bb = swz >> 10, pb = (swz >> 5) & 31, kb = swz & 31;
  const int pbase = pb * 32, kbase = kb * 32;

  if (kbase > pbase + 31) {  // fully masked: w=0 for all heads -> out = ln_bias
#pragma unroll
    for (int it = 0; it < 8; it++) {
      int idx = it * 512 + tid;            // 0..4095 quads
      int s = idx >> 8, rem = idx & 255;   // 16 heads x (32p x 8 quads)
      int pl = rem >> 3, kq = (rem & 7) * 4;
      float bv = ln_bias[s];
      f32x4_t v = {bv, bv, bv, bv};
      __builtin_nontemporal_store(
          v, (f32x4_t*)(out + ((size_t)(bb * 16 + s) * 1024 + pbase + pl) * 1024 + kbase + kq));
    }
    return;
  }

  __shared__ float part_sum[8][1024];  // [wave][cell = prl*32+col]
  __shared__ float part_ssq[8][1024];
  __shared__ float mu_lds[1024];
  __shared__ float rs_lds[1024];
  __shared__ float rl_lds[16][32];

  const int col = lane & 31, hi = lane >> 5;
  const int kcol = kbase + col;

  // stage rl (16 heads x 32 p-rows), one entry per thread
  {
    int s = tid >> 5, pr = tid & 31;
    rl_lds[s][pr] = rl_ws[(size_t)(bb * 16 + s) * 1024 + pbase + pr];
  }

  f32x16_t c[2];
#pragma unroll
  for (int sp = 0; sp < 2; sp++)
#pragma unroll
    for (int j = 0; j < 16; j++) c[sp][j] = 0.f;

  // score tiles for this wave's 2 heads: A=Q (rows=p), B=K (rows=k)
#pragma unroll
  for (int sp = 0; sp < 2; sp++) {
    int s = w * 2 + sp;
    size_t base = (size_t)(bb * 16 + s) * 65536;
    const bf16_t* qrow = q_ws + base + (size_t)(pbase + col) * 64 + hi * 8;
    const bf16_t* krow = k_ws + base + (size_t)kcol * 64 + hi * 8;
    bf16x8_t qa[4], kv[4];
#pragma unroll
    for (int t = 0; t < 4; t++) {
      qa[t] = *(const bf16x8_t*)(qrow + t * 16);
      kv[t] = *(const bf16x8_t*)(krow + t * 16);
    }
#pragma unroll
    for (int t = 0; t < 4; t++)
      c[sp] = __builtin_amdgcn_mfma_f32_32x32x16_bf16(qa[t], kv[t], c[sp], 0, 0, 0);
  }

  __syncthreads();  // rl_lds ready

  // w = exp(score)*rl (causal); per-wave (2-head) partial stats per cell
  float sum_p[16], ssq_p[16];
#pragma unroll
  for (int j = 0; j < 16; j++) { sum_p[j] = 0.f; ssq_p[j] = 0.f; }
#pragma unroll
  for (int sp = 0; sp < 2; sp++) {
    int s = w * 2 + sp;
#pragma unroll
    for (int j = 0; j < 16; j++) {
      int prl = (j & 3) + 8 * (j >> 2) + 4 * hi;   // p-row within tile
      float wv = (kcol <= pbase + prl) ? exp2f(c[sp][j] * kLog2e) * rl_lds[s][prl] : 0.f;
      c[sp][j] = wv;
      sum_p[j] += wv;
      ssq_p[j] = fmaf(wv, wv, ssq_p[j]);
    }
  }

#pragma unroll
  for (int j = 0; j < 16; j++) {
    int prl = (j & 3) + 8 * (j >> 2) + 4 * hi;
    int cell = prl * 32 + col;
    part_sum[w][cell] = sum_p[j];
    part_ssq[w][cell] = ssq_p[j];
  }
  __syncthreads();

  // stage 2: threads 0..255 reduce 4 cells each via f32x4 LDS reads
  if (tid < 256) {
    int q4 = tid * 4;
    f32x4_t s4 = {0.f, 0.f, 0.f, 0.f}, qq = {0.f, 0.f, 0.f, 0.f};
#pragma unroll
    for (int i = 0; i < 8; i++) {
      s4 += *(const f32x4_t*)&part_sum[i][q4];
      qq += *(const f32x4_t*)&part_ssq[i][q4];
    }
    f32x4_t m = s4 * 0.0625f;
    f32x4_t var = qq * 0.0625f - m * m;
    f32x4_t r;
#pragma unroll
    for (int e = 0; e < 4; e++) r[e] = rsqrtf(var[e] + 1e-5f);
    *(f32x4_t*)&mu_lds[q4] = m;
    *(f32x4_t*)&rs_lds[q4] = r;
  }
  __syncthreads();

  float mu[16], rs[16];
#pragma unroll
  for (int j = 0; j < 16; j++) {
    int prl = (j & 3) + 8 * (j >> 2) + 4 * hi;
    int cell = prl * 32 + col;
    mu[j] = mu_lds[cell];
    rs[j] = rs_lds[cell];
  }

  // stores: scalar dwords, nontemporal; lanes 0-31 cover 128B of row prl,
  // lanes 32-63 row prl+4 -> 2 dense 128B segments per instruction.
#pragma unroll
  for (int sp = 0; sp < 2; sp++) {
    int s = w * 2 + sp;
    float scl = ln_scale[s], bi = ln_bias[s];
    size_t hb = ((size_t)(bb * 16 + s) * 1024 + pbase) * 1024 + kbase;
#pragma unroll
    for (int j = 0; j < 16; j++) {
      int prl = (j & 3) + 8 * (j >> 2) + 4 * hi;
      __builtin_nontemporal_store((c[sp][j] - mu[j]) * rs[j] * scl + bi,
                                  &out[hb + (size_t)prl * 1024 + col]);
    }
  }
}

extern "C" void kernel_launch(void* const* d_in, const int* in_sizes, int n_in,
                              void* d_out, int out_size, void* d_ws, size_t ws_size,
                              hipStream_t stream) {
  (void)in_sizes; (void)n_in; (void)out_size; (void)ws_size;
  const float* x        = (const float*)d_in[0];
  // d_in[1] = mask (causal tril; structure hardcoded)
  const float* W        = (const float*)d_in[2];
  const float* bias     = (const float*)d_in[3];
  const float* ln_scale = (const float*)d_in[4];
  const float* ln_bias  = (const float*)d_in[5];
  float* out = (float*)d_out;

  char* ws = (char*)d_ws;
  bf16_t* q_ws = (bf16_t*)ws;                    //  8,388,608 B [b][s][p][h]
  bf16_t* k_ws = (bf16_t*)(ws + 8388608);        //  8,388,608 B
  float*  rl_ws = (float*)(ws + 16777216);       //    262,144 B [b][s][p]
  bf16_t* xb   = (bf16_t*)(ws + 17039360);       //  6,291,456 B [4096][768]
  bf16_t* Wt   = (bf16_t*)(ws + 23330816);       //  3,145,728 B [2048][768]

  k_cvt_x<<<dim3(1536), 256, 0, stream>>>(x, xb);
  k_tr_w <<<dim3(64, 24), 256, 0, stream>>>(W, Wt);
  k_proj <<<dim3(16, 32), 256, 0, stream>>>(xb, Wt, bias, q_ws, k_ws);
  k_sumexp<<<dim3(16, 64), 256, 0, stream>>>(q_ws, k_ws, rl_ws);
  k_final<<<dim3(4096), 512, 0, stream>>>(q_ws, k_ws, rl_ws, ln_scale, ln_bias, out);
}